// Round 1
// baseline (1825.296 us; speedup 1.0000x reference)
//
#include <hip/hip_runtime.h>
#include <hip/hip_bf16.h>

#define N_NODES 50000
#define N_EDGES 3200000

__device__ __forceinline__ float elu_f(float x) { return x > 0.f ? x : (expf(x) - 1.f); }

// ---------------- fused maxpool(2) + LayerNorm(1024) ----------------
// one block (256 threads) per node: read 2048 f32, pool pairs -> 1024, LN -> h0
__global__ void pool_ln_kernel(const float* __restrict__ x,
                               const float* __restrict__ ln_w,
                               const float* __restrict__ ln_b,
                               float* __restrict__ h0) {
    int node = blockIdx.x;
    int t = threadIdx.x;
    const float4* xr = (const float4*)(x + (size_t)node * 2048);
    float4 a = xr[t];
    float4 b = xr[t + 256];
    float p0 = fmaxf(a.x, a.y), p1 = fmaxf(a.z, a.w);
    float p2 = fmaxf(b.x, b.y), p3 = fmaxf(b.z, b.w);
    float sum = p0 + p1 + p2 + p3;
    float sq  = p0*p0 + p1*p1 + p2*p2 + p3*p3;
    // wave (64) reduce
    #pragma unroll
    for (int off = 32; off > 0; off >>= 1) {
        sum += __shfl_down(sum, off);
        sq  += __shfl_down(sq, off);
    }
    __shared__ float red_s[4], red_q[4];
    __shared__ float s_mu, s_rstd;
    int wave = t >> 6, lane = t & 63;
    if (lane == 0) { red_s[wave] = sum; red_q[wave] = sq; }
    __syncthreads();
    if (t == 0) {
        float S = red_s[0] + red_s[1] + red_s[2] + red_s[3];
        float Q = red_q[0] + red_q[1] + red_q[2] + red_q[3];
        float mu = S * (1.f / 1024.f);
        float var = Q * (1.f / 1024.f) - mu * mu;
        s_mu = mu;
        s_rstd = rsqrtf(var + 1e-5f);
    }
    __syncthreads();
    float mu = s_mu, rstd = s_rstd;
    float* out = h0 + (size_t)node * 1024;
    int i0 = 2 * t;       // pooled idx of p0,p1
    int i1 = 512 + 2 * t; // pooled idx of p2,p3
    out[i0]     = (p0 - mu) * rstd * ln_w[i0]     + ln_b[i0];
    out[i0 + 1] = (p1 - mu) * rstd * ln_w[i0 + 1] + ln_b[i0 + 1];
    out[i1]     = (p2 - mu) * rstd * ln_w[i1]     + ln_b[i1];
    out[i1 + 1] = (p3 - mu) * rstd * ln_w[i1 + 1] + ln_b[i1 + 1];
}

// ---------------- generic fp32 GEMM: C = act(A[M,K] @ W[K,N] + bias) ----------------
// 64x64 tile, 256 threads, 4x4 per thread, guarded for ragged M/N.
__global__ void gemm_kernel(const float* __restrict__ A, const float* __restrict__ W,
                            const float* __restrict__ bias, float* __restrict__ C,
                            int M, int N, int K, int do_elu) {
    const int BM = 64, BN = 64, BK = 16;
    __shared__ float As[BK][BM + 4];
    __shared__ float Ws[BK][BN + 4];
    int tid = threadIdx.x;
    int tx = tid & 15, ty = tid >> 4;
    int m0 = blockIdx.x * BM;
    int n0 = blockIdx.y * BN;
    float acc[4][4] = {};
    for (int k0 = 0; k0 < K; k0 += BK) {
        #pragma unroll
        for (int l = 0; l < 4; ++l) {
            int idx = tid + l * 256;      // 0..1023 -> 64 rows x 16 k
            int r = idx >> 4, c = idx & 15;
            int m = m0 + r;
            As[c][r] = (m < M) ? A[(size_t)m * K + k0 + c] : 0.f;
        }
        #pragma unroll
        for (int l = 0; l < 4; ++l) {
            int idx = tid + l * 256;      // 16 k x 64 n
            int c = idx >> 6, n = idx & 63;
            int nn = n0 + n;
            Ws[c][n] = (nn < N) ? W[(size_t)(k0 + c) * N + nn] : 0.f;
        }
        __syncthreads();
        #pragma unroll
        for (int kk = 0; kk < BK; ++kk) {
            float4 av = *(const float4*)&As[kk][ty * 4];
            float4 wv = *(const float4*)&Ws[kk][tx * 4];
            float ar[4] = {av.x, av.y, av.z, av.w};
            float wr[4] = {wv.x, wv.y, wv.z, wv.w};
            #pragma unroll
            for (int i = 0; i < 4; ++i)
                #pragma unroll
                for (int j = 0; j < 4; ++j)
                    acc[i][j] += ar[i] * wr[j];
        }
        __syncthreads();
    }
    #pragma unroll
    for (int i = 0; i < 4; ++i) {
        int m = m0 + ty * 4 + i;
        if (m >= M) continue;
        #pragma unroll
        for (int j = 0; j < 4; ++j) {
            int n = n0 + tx * 4 + j;
            if (n >= N) continue;
            float v = acc[i][j] + (bias ? bias[n] : 0.f);
            if (do_elu) v = elu_f(v);
            C[(size_t)m * N + n] = v;
        }
    }
}

// ---------------- degree / rsqrt ----------------
__global__ void deg_init_kernel(float* __restrict__ deg) {
    int i = blockIdx.x * blockDim.x + threadIdx.x;
    if (i < N_NODES) deg[i] = 1.f;  // self loop
}
__global__ void deg_count_kernel(const int* __restrict__ col, float* __restrict__ deg) {
    int e = blockIdx.x * blockDim.x + threadIdx.x;
    if (e < N_EDGES) atomicAdd(&deg[col[e]], 1.f);
}
__global__ void deg_rsqrt_kernel(float* __restrict__ deg) {
    int i = blockIdx.x * blockDim.x + threadIdx.x;
    if (i < N_NODES) deg[i] = rsqrtf(deg[i]);
}

// ---------------- GCN aggregation ----------------
// init with self-loop contribution: out[i,f] = dis[i]^2 * xw[i,f]
__global__ void agg_init_kernel(const float* __restrict__ xw, const float* __restrict__ dis,
                                float* __restrict__ out, int fshift) {
    int idx = blockIdx.x * blockDim.x + threadIdx.x;
    int total = N_NODES << fshift;
    if (idx < total) {
        int i = idx >> fshift;
        float d = dis[i];
        out[idx] = d * d * xw[idx];
    }
}
// out[col,f] += dis[row]*dis[col]*xw[row,f] for every edge
__global__ void agg_edges_kernel(const float* __restrict__ xw, const int* __restrict__ row,
                                 const int* __restrict__ col, const float* __restrict__ dis,
                                 float* __restrict__ out, int fshift) {
    long long idx = (long long)blockIdx.x * blockDim.x + threadIdx.x;
    long long total = (long long)N_EDGES << fshift;
    if (idx >= total) return;
    int e = (int)(idx >> fshift);
    int f = (int)(idx & ((1 << fshift) - 1));
    int r = row[e], c = col[e];
    float v = dis[r] * dis[c] * xw[((size_t)r << fshift) + f];
    atomicAdd(&out[((size_t)c << fshift) + f], v);
}
__global__ void bias_act_kernel(float* __restrict__ h, const float* __restrict__ bias,
                                int fshift, int do_elu) {
    int idx = blockIdx.x * blockDim.x + threadIdx.x;
    int total = N_NODES << fshift;
    if (idx < total) {
        int f = idx & ((1 << fshift) - 1);
        float v = h[idx] + bias[f];
        h[idx] = do_elu ? elu_f(v) : v;
    }
}

extern "C" void kernel_launch(void* const* d_in, const int* in_sizes, int n_in,
                              void* d_out, int out_size, void* d_ws, size_t ws_size,
                              hipStream_t stream) {
    const float* x    = (const float*)d_in[0];
    const int*   ei   = (const int*)d_in[1];
    const int*   row  = ei;
    const int*   col  = ei + N_EDGES;
    const float* ln_w = (const float*)d_in[2];
    const float* ln_b = (const float*)d_in[3];
    const float* w0   = (const float*)d_in[4];
    const float* b0   = (const float*)d_in[5];
    const float* w1   = (const float*)d_in[6];
    const float* b1   = (const float*)d_in[7];
    const float* w2   = (const float*)d_in[8];
    const float* b2   = (const float*)d_in[9];
    const float* g1w  = (const float*)d_in[10];
    const float* g1b  = (const float*)d_in[11];
    const float* g2w  = (const float*)d_in[12];
    const float* g2b  = (const float*)d_in[13];
    float* out = (float*)d_out;

    float* ws = (float*)d_ws;
    // float offsets into ws (h2/h3/... overlay dead h0)
    float* h0   = ws + 0;           // 50000*1024
    float* h1   = ws + 51200000;    // 50000*512
    float* h2   = ws + 0;           // 50000*128 (overlays h0)
    float* h3   = ws + 6400000;     // 50000*64
    float* dis  = ws + 9600000;     // 50000
    float* xw1  = ws + 9650000;     // 50000*32
    float* agg1 = ws + 11250000;    // 50000*32
    float* xw2  = ws + 12850000;    // 50000*16

    // 1. pool + layernorm
    pool_ln_kernel<<<N_NODES, 256, 0, stream>>>(x, ln_w, ln_b, h0);

    // 2-4. MLP
    {
        dim3 g((N_NODES + 63) / 64, 512 / 64);
        gemm_kernel<<<g, 256, 0, stream>>>(h0, w0, b0, h1, N_NODES, 512, 1024, 1);
    }
    {
        dim3 g((N_NODES + 63) / 64, 128 / 64);
        gemm_kernel<<<g, 256, 0, stream>>>(h1, w1, b1, h2, N_NODES, 128, 512, 1);
    }
    {
        dim3 g((N_NODES + 63) / 64, 1);
        gemm_kernel<<<g, 256, 0, stream>>>(h2, w2, b2, h3, N_NODES, 64, 128, 1);
    }

    // 5. degrees -> dis
    deg_init_kernel<<<(N_NODES + 255) / 256, 256, 0, stream>>>(dis);
    deg_count_kernel<<<(N_EDGES + 255) / 256, 256, 0, stream>>>(col, dis);
    deg_rsqrt_kernel<<<(N_NODES + 255) / 256, 256, 0, stream>>>(dis);

    // 6. GCN1: xw1 = h3 @ g1w  (no bias yet)
    {
        dim3 g((N_NODES + 63) / 64, 1);
        gemm_kernel<<<g, 256, 0, stream>>>(h3, g1w, nullptr, xw1, N_NODES, 32, 64, 0);
    }
    // 7. aggregate + bias + ELU
    agg_init_kernel<<<((N_NODES * 32) + 255) / 256, 256, 0, stream>>>(xw1, dis, agg1, 5);
    {
        long long total = (long long)N_EDGES * 32;
        int blocks = (int)((total + 255) / 256);
        agg_edges_kernel<<<blocks, 256, 0, stream>>>(xw1, row, col, dis, agg1, 5);
    }
    bias_act_kernel<<<((N_NODES * 32) + 255) / 256, 256, 0, stream>>>(agg1, g1b, 5, 1);

    // 8. GCN2: xw2 = agg1 @ g2w
    {
        dim3 g((N_NODES + 63) / 64, 1);
        gemm_kernel<<<g, 256, 0, stream>>>(agg1, g2w, nullptr, xw2, N_NODES, 16, 32, 0);
    }
    // 9. aggregate into d_out + bias (no ELU)
    agg_init_kernel<<<((N_NODES * 16) + 255) / 256, 256, 0, stream>>>(xw2, dis, out, 4);
    {
        long long total = (long long)N_EDGES * 16;
        int blocks = (int)((total + 255) / 256);
        agg_edges_kernel<<<blocks, 256, 0, stream>>>(xw2, row, col, dis, out, 4);
    }
    bias_act_kernel<<<((N_NODES * 16) + 255) / 256, 256, 0, stream>>>(out, g2b, 4, 0);
}

// Round 2
// 986.359 us; speedup vs baseline: 1.8505x; 1.8505x over previous
//
#include <hip/hip_runtime.h>
#include <hip/hip_bf16.h>

#define N_NODES 50000
#define N_EDGES 3200000

typedef __bf16 v8bf __attribute__((ext_vector_type(8)));
typedef float v4f __attribute__((ext_vector_type(4)));
typedef unsigned short u16x8 __attribute__((ext_vector_type(8)));

__device__ __forceinline__ float elu_f(float x) { return x > 0.f ? x : (expf(x) - 1.f); }

// ---------------- fused maxpool(2) + LayerNorm(1024) -> bf16 ----------------
__global__ void pool_ln_kernel(const float* __restrict__ x,
                               const float* __restrict__ ln_w,
                               const float* __restrict__ ln_b,
                               __bf16* __restrict__ h0) {
    int node = blockIdx.x;
    int t = threadIdx.x;
    const float4* xr = (const float4*)(x + (size_t)node * 2048);
    float4 a = xr[t];
    float4 b = xr[t + 256];
    float p0 = fmaxf(a.x, a.y), p1 = fmaxf(a.z, a.w);
    float p2 = fmaxf(b.x, b.y), p3 = fmaxf(b.z, b.w);
    float sum = p0 + p1 + p2 + p3;
    float sq  = p0*p0 + p1*p1 + p2*p2 + p3*p3;
    #pragma unroll
    for (int off = 32; off > 0; off >>= 1) {
        sum += __shfl_down(sum, off);
        sq  += __shfl_down(sq, off);
    }
    __shared__ float red_s[4], red_q[4];
    __shared__ float s_mu, s_rstd;
    int wave = t >> 6, lane = t & 63;
    if (lane == 0) { red_s[wave] = sum; red_q[wave] = sq; }
    __syncthreads();
    if (t == 0) {
        float S = red_s[0] + red_s[1] + red_s[2] + red_s[3];
        float Q = red_q[0] + red_q[1] + red_q[2] + red_q[3];
        float mu = S * (1.f / 1024.f);
        float var = Q * (1.f / 1024.f) - mu * mu;
        s_mu = mu;
        s_rstd = rsqrtf(var + 1e-5f);
    }
    __syncthreads();
    float mu = s_mu, rstd = s_rstd;
    __bf16* out = h0 + (size_t)node * 1024;
    int i0 = 2 * t;
    int i1 = 512 + 2 * t;
    out[i0]     = (__bf16)((p0 - mu) * rstd * ln_w[i0]     + ln_b[i0]);
    out[i0 + 1] = (__bf16)((p1 - mu) * rstd * ln_w[i0 + 1] + ln_b[i0 + 1]);
    out[i1]     = (__bf16)((p2 - mu) * rstd * ln_w[i1]     + ln_b[i1]);
    out[i1 + 1] = (__bf16)((p3 - mu) * rstd * ln_w[i1 + 1] + ln_b[i1 + 1]);
}

// ---------------- W[K][N] fp32 -> WT[N][K] bf16 ----------------
__global__ void wt_kernel(const float* __restrict__ W, __bf16* __restrict__ WT,
                          int K, int N) {
    int idx = blockIdx.x * 256 + threadIdx.x;
    if (idx < K * N) {
        int k = idx / N, n = idx - k * N;
        WT[(size_t)n * K + k] = (__bf16)W[idx];
    }
}

// ---------------- bf16 MFMA GEMM: C = act(A[M,K] @ B[K,N] + bias) ----------------
// A bf16 row-major, BT bf16 [N][K]. 128x128 tile, BK=32, 4 waves (2x2), each
// wave 64x64 = 4x4 fragments of 16x16x32. Reg-staged LDS, padded rows (80B).
__global__ __launch_bounds__(256) void mfma_gemm(
    const __bf16* __restrict__ A, const __bf16* __restrict__ BT,
    const float* __restrict__ bias, void* __restrict__ C,
    int M, int N, int K, int do_elu, int out_bf16)
{
    // rows padded to 40 ushorts (80B = 5*16B -> 16B-aligned, 2-way-free banks)
    __shared__ unsigned short lds[2 * 128 * 40];  // As | Bs, 20.0 KiB
    const int tid  = threadIdx.x;
    const int lane = tid & 63, wave = tid >> 6;
    const int wr = wave >> 1, wc = wave & 1;
    const int m0 = blockIdx.x * 128, n0 = blockIdx.y * 128;

    // staging: 512 16B segs per operand; thread handles segs {tid, tid+256}
    size_t offA[2], offB[2];
    int dstA[2], dstB[2];
    #pragma unroll
    for (int i = 0; i < 2; ++i) {
        int s = tid + i * 256;
        int r = s >> 2, ks = s & 3;
        int gr = m0 + r; if (gr > M - 1) gr = M - 1;
        offA[i] = (size_t)gr * K + ks * 8;
        dstA[i] = r * 40 + ks * 8;
        int gc = n0 + r; if (gc > N - 1) gc = N - 1;
        offB[i] = (size_t)gc * K + ks * 8;
        dstB[i] = 5120 + r * 40 + ks * 8;
    }

    v4f acc[4][4] = {};
    const int l15 = lane & 15, l4 = lane >> 4;
    const int abase = (wr * 64 + l15) * 40 + l4 * 8;
    const int bbase = 5120 + (wc * 64 + l15) * 40 + l4 * 8;

    u16x8 sa0 = *(const u16x8*)(A + offA[0]);
    u16x8 sa1 = *(const u16x8*)(A + offA[1]);
    u16x8 sb0 = *(const u16x8*)(BT + offB[0]);
    u16x8 sb1 = *(const u16x8*)(BT + offB[1]);

    for (int k0 = 0; k0 < K; k0 += 32) {
        __syncthreads();
        *(u16x8*)&lds[dstA[0]] = sa0;
        *(u16x8*)&lds[dstA[1]] = sa1;
        *(u16x8*)&lds[dstB[0]] = sb0;
        *(u16x8*)&lds[dstB[1]] = sb1;
        if (k0 + 32 < K) {  // prefetch next tile into regs (hides HBM latency)
            sa0 = *(const u16x8*)(A + offA[0] + k0 + 32);
            sa1 = *(const u16x8*)(A + offA[1] + k0 + 32);
            sb0 = *(const u16x8*)(BT + offB[0] + k0 + 32);
            sb1 = *(const u16x8*)(BT + offB[1] + k0 + 32);
        }
        __syncthreads();
        v8bf af[4], bfr[4];
        #pragma unroll
        for (int m = 0; m < 4; ++m) af[m]  = *(const v8bf*)&lds[abase + m * 16 * 40];
        #pragma unroll
        for (int n = 0; n < 4; ++n) bfr[n] = *(const v8bf*)&lds[bbase + n * 16 * 40];
        #pragma unroll
        for (int m = 0; m < 4; ++m)
            #pragma unroll
            for (int n = 0; n < 4; ++n)
                acc[m][n] = __builtin_amdgcn_mfma_f32_16x16x32_bf16(af[m], bfr[n], acc[m][n], 0, 0, 0);
    }

    // C/D layout: col = lane&15, row = (lane>>4)*4 + j   [m89 verified]
    #pragma unroll
    for (int m = 0; m < 4; ++m) {
        #pragma unroll
        for (int j = 0; j < 4; ++j) {
            int row = m0 + wr * 64 + m * 16 + l4 * 4 + j;
            if (row >= M) continue;
            #pragma unroll
            for (int n = 0; n < 4; ++n) {
                int col = n0 + wc * 64 + n * 16 + l15;
                if (col >= N) continue;
                float v = acc[m][n][j] + bias[col];
                if (do_elu) v = elu_f(v);
                if (out_bf16) ((__bf16*)C)[(size_t)row * N + col] = (__bf16)v;
                else          ((float*)C)[(size_t)row * N + col] = v;
            }
        }
    }
}

// ---------------- small fp32 GEMM (GCN feature transforms) ----------------
__global__ void gemm_kernel(const float* __restrict__ A, const float* __restrict__ W,
                            const float* __restrict__ bias, float* __restrict__ C,
                            int M, int N, int K, int do_elu) {
    const int BM = 64, BN = 64, BK = 16;
    __shared__ float As[BK][BM + 4];
    __shared__ float Ws[BK][BN + 4];
    int tid = threadIdx.x;
    int tx = tid & 15, ty = tid >> 4;
    int m0 = blockIdx.x * BM;
    int n0 = blockIdx.y * BN;
    float acc[4][4] = {};
    for (int k0 = 0; k0 < K; k0 += BK) {
        #pragma unroll
        for (int l = 0; l < 4; ++l) {
            int idx = tid + l * 256;
            int r = idx >> 4, c = idx & 15;
            int m = m0 + r;
            As[c][r] = (m < M) ? A[(size_t)m * K + k0 + c] : 0.f;
        }
        #pragma unroll
        for (int l = 0; l < 4; ++l) {
            int idx = tid + l * 256;
            int c = idx >> 6, n = idx & 63;
            int nn = n0 + n;
            Ws[c][n] = (nn < N) ? W[(size_t)(k0 + c) * N + nn] : 0.f;
        }
        __syncthreads();
        #pragma unroll
        for (int kk = 0; kk < BK; ++kk) {
            float4 av = *(const float4*)&As[kk][ty * 4];
            float4 wv = *(const float4*)&Ws[kk][tx * 4];
            float ar[4] = {av.x, av.y, av.z, av.w};
            float wrg[4] = {wv.x, wv.y, wv.z, wv.w};
            #pragma unroll
            for (int i = 0; i < 4; ++i)
                #pragma unroll
                for (int j = 0; j < 4; ++j)
                    acc[i][j] += ar[i] * wrg[j];
        }
        __syncthreads();
    }
    #pragma unroll
    for (int i = 0; i < 4; ++i) {
        int m = m0 + ty * 4 + i;
        if (m >= M) continue;
        #pragma unroll
        for (int j = 0; j < 4; ++j) {
            int n = n0 + tx * 4 + j;
            if (n >= N) continue;
            float v = acc[i][j] + (bias ? bias[n] : 0.f);
            if (do_elu) v = elu_f(v);
            C[(size_t)m * N + n] = v;
        }
    }
}

// ---------------- degree / rsqrt ----------------
__global__ void deg_init_kernel(float* __restrict__ deg) {
    int i = blockIdx.x * blockDim.x + threadIdx.x;
    if (i < N_NODES) deg[i] = 1.f;
}
__global__ void deg_count_kernel(const int* __restrict__ col, float* __restrict__ deg) {
    int e = blockIdx.x * blockDim.x + threadIdx.x;
    if (e < N_EDGES) atomicAdd(&deg[col[e]], 1.f);
}
__global__ void deg_rsqrt_kernel(float* __restrict__ deg) {
    int i = blockIdx.x * blockDim.x + threadIdx.x;
    if (i < N_NODES) deg[i] = rsqrtf(deg[i]);
}

// ---------------- GCN aggregation ----------------
__global__ void agg_init_kernel(const float* __restrict__ xw, const float* __restrict__ dis,
                                float* __restrict__ out, int fshift) {
    int idx = blockIdx.x * blockDim.x + threadIdx.x;
    int total = N_NODES << fshift;
    if (idx < total) {
        int i = idx >> fshift;
        float d = dis[i];
        out[idx] = d * d * xw[idx];
    }
}
__global__ void agg_edges_kernel(const float* __restrict__ xw, const int* __restrict__ row,
                                 const int* __restrict__ col, const float* __restrict__ dis,
                                 float* __restrict__ out, int fshift) {
    long long idx = (long long)blockIdx.x * blockDim.x + threadIdx.x;
    long long total = (long long)N_EDGES << fshift;
    if (idx >= total) return;
    int e = (int)(idx >> fshift);
    int f = (int)(idx & ((1 << fshift) - 1));
    int r = row[e], c = col[e];
    float v = dis[r] * dis[c] * xw[((size_t)r << fshift) + f];
    atomicAdd(&out[((size_t)c << fshift) + f], v);
}
__global__ void bias_act_kernel(float* __restrict__ h, const float* __restrict__ bias,
                                int fshift, int do_elu) {
    int idx = blockIdx.x * blockDim.x + threadIdx.x;
    int total = N_NODES << fshift;
    if (idx < total) {
        int f = idx & ((1 << fshift) - 1);
        float v = h[idx] + bias[f];
        h[idx] = do_elu ? elu_f(v) : v;
    }
}

extern "C" void kernel_launch(void* const* d_in, const int* in_sizes, int n_in,
                              void* d_out, int out_size, void* d_ws, size_t ws_size,
                              hipStream_t stream) {
    const float* x    = (const float*)d_in[0];
    const int*   ei   = (const int*)d_in[1];
    const int*   row  = ei;
    const int*   col  = ei + N_EDGES;
    const float* ln_w = (const float*)d_in[2];
    const float* ln_b = (const float*)d_in[3];
    const float* w0   = (const float*)d_in[4];
    const float* b0   = (const float*)d_in[5];
    const float* w1   = (const float*)d_in[6];
    const float* b1   = (const float*)d_in[7];
    const float* w2   = (const float*)d_in[8];
    const float* b2   = (const float*)d_in[9];
    const float* g1w  = (const float*)d_in[10];
    const float* g1b  = (const float*)d_in[11];
    const float* g2w  = (const float*)d_in[12];
    const float* g2b  = (const float*)d_in[13];
    float* out = (float*)d_out;

    char* W = (char*)d_ws;
    __bf16* h0  = (__bf16*)(W + 0);          // 50000*1024 bf16
    __bf16* h1  = (__bf16*)(W + 102400000);  // 50000*512 bf16
    __bf16* h2  = (__bf16*)(W + 153600000);  // 50000*128 bf16
    float*  h3  = (float*) (W + 166400000);  // 50000*64 f32
    float*  dis = (float*) (W + 179200000);  // 50000 f32
    float*  xw1 = (float*) (W + 179400192);  // 50000*32 f32
    float*  agg1= (float*) (W + 185800192);  // 50000*32 f32
    float*  xw2 = (float*) (W + 192200192);  // 50000*16 f32
    __bf16* w0t = (__bf16*)(W + 195400192);  // 512*1024 bf16
    __bf16* w1t = (__bf16*)(W + 196448768);  // 128*512 bf16
    __bf16* w2t = (__bf16*)(W + 196579840);  // 64*128 bf16

    // weight transposes (tiny)
    wt_kernel<<<(1024 * 512 + 255) / 256, 256, 0, stream>>>(w0, w0t, 1024, 512);
    wt_kernel<<<(512 * 128 + 255) / 256, 256, 0, stream>>>(w1, w1t, 512, 128);
    wt_kernel<<<(128 * 64 + 255) / 256, 256, 0, stream>>>(w2, w2t, 128, 64);

    // 1. pool + layernorm -> bf16
    pool_ln_kernel<<<N_NODES, 256, 0, stream>>>(x, ln_w, ln_b, h0);

    // 2-4. MLP on MFMA
    {
        dim3 g((N_NODES + 127) / 128, 4);
        mfma_gemm<<<g, 256, 0, stream>>>(h0, w0t, b0, h1, N_NODES, 512, 1024, 1, 1);
    }
    {
        dim3 g((N_NODES + 127) / 128, 1);
        mfma_gemm<<<g, 256, 0, stream>>>(h1, w1t, b1, h2, N_NODES, 128, 512, 1, 1);
    }
    {
        dim3 g((N_NODES + 127) / 128, 1);
        mfma_gemm<<<g, 256, 0, stream>>>(h2, w2t, b2, h3, N_NODES, 64, 128, 1, 0);
    }

    // 5. degrees -> dis
    deg_init_kernel<<<(N_NODES + 255) / 256, 256, 0, stream>>>(dis);
    deg_count_kernel<<<(N_EDGES + 255) / 256, 256, 0, stream>>>(col, dis);
    deg_rsqrt_kernel<<<(N_NODES + 255) / 256, 256, 0, stream>>>(dis);

    // 6. GCN1: xw1 = h3 @ g1w
    {
        dim3 g((N_NODES + 63) / 64, 1);
        gemm_kernel<<<g, 256, 0, stream>>>(h3, g1w, nullptr, xw1, N_NODES, 32, 64, 0);
    }
    // 7. aggregate + bias + ELU
    agg_init_kernel<<<((N_NODES * 32) + 255) / 256, 256, 0, stream>>>(xw1, dis, agg1, 5);
    {
        long long total = (long long)N_EDGES * 32;
        int blocks = (int)((total + 255) / 256);
        agg_edges_kernel<<<blocks, 256, 0, stream>>>(xw1, row, col, dis, agg1, 5);
    }
    bias_act_kernel<<<((N_NODES * 32) + 255) / 256, 256, 0, stream>>>(agg1, g1b, 5, 1);

    // 8. GCN2: xw2 = agg1 @ g2w
    {
        dim3 g((N_NODES + 63) / 64, 1);
        gemm_kernel<<<g, 256, 0, stream>>>(agg1, g2w, nullptr, xw2, N_NODES, 16, 32, 0);
    }
    // 9. aggregate into d_out + bias (no ELU)
    agg_init_kernel<<<((N_NODES * 16) + 255) / 256, 256, 0, stream>>>(xw2, dis, out, 4);
    {
        long long total = (long long)N_EDGES * 16;
        int blocks = (int)((total + 255) / 256);
        agg_edges_kernel<<<blocks, 256, 0, stream>>>(xw2, row, col, dis, out, 4);
    }
    bias_act_kernel<<<((N_NODES * 16) + 255) / 256, 256, 0, stream>>>(out, g2b, 4, 0);
}

// Round 3
// 889.427 us; speedup vs baseline: 2.0522x; 1.1090x over previous
//
#include <hip/hip_runtime.h>
#include <hip/hip_bf16.h>

#define N_NODES 50000
#define N_EDGES 3200000

typedef __bf16 v8bf __attribute__((ext_vector_type(8)));
typedef float v4f __attribute__((ext_vector_type(4)));
typedef unsigned short u16x8 __attribute__((ext_vector_type(8)));

__device__ __forceinline__ float elu_f(float x) { return x > 0.f ? x : (expf(x) - 1.f); }

// ---------------- fused maxpool(2) + LayerNorm(1024) -> bf16 ----------------
__global__ void pool_ln_kernel(const float* __restrict__ x,
                               const float* __restrict__ ln_w,
                               const float* __restrict__ ln_b,
                               __bf16* __restrict__ h0) {
    int node = blockIdx.x;
    int t = threadIdx.x;
    const float4* xr = (const float4*)(x + (size_t)node * 2048);
    float4 a = xr[t];
    float4 b = xr[t + 256];
    float p0 = fmaxf(a.x, a.y), p1 = fmaxf(a.z, a.w);
    float p2 = fmaxf(b.x, b.y), p3 = fmaxf(b.z, b.w);
    float sum = p0 + p1 + p2 + p3;
    float sq  = p0*p0 + p1*p1 + p2*p2 + p3*p3;
    #pragma unroll
    for (int off = 32; off > 0; off >>= 1) {
        sum += __shfl_down(sum, off);
        sq  += __shfl_down(sq, off);
    }
    __shared__ float red_s[4], red_q[4];
    __shared__ float s_mu, s_rstd;
    int wave = t >> 6, lane = t & 63;
    if (lane == 0) { red_s[wave] = sum; red_q[wave] = sq; }
    __syncthreads();
    if (t == 0) {
        float S = red_s[0] + red_s[1] + red_s[2] + red_s[3];
        float Q = red_q[0] + red_q[1] + red_q[2] + red_q[3];
        float mu = S * (1.f / 1024.f);
        float var = Q * (1.f / 1024.f) - mu * mu;
        s_mu = mu;
        s_rstd = rsqrtf(var + 1e-5f);
    }
    __syncthreads();
    float mu = s_mu, rstd = s_rstd;
    __bf16* out = h0 + (size_t)node * 1024;
    int i0 = 2 * t;
    int i1 = 512 + 2 * t;
    out[i0]     = (__bf16)((p0 - mu) * rstd * ln_w[i0]     + ln_b[i0]);
    out[i0 + 1] = (__bf16)((p1 - mu) * rstd * ln_w[i0 + 1] + ln_b[i0 + 1]);
    out[i1]     = (__bf16)((p2 - mu) * rstd * ln_w[i1]     + ln_b[i1]);
    out[i1 + 1] = (__bf16)((p3 - mu) * rstd * ln_w[i1 + 1] + ln_b[i1 + 1]);
}

// ---------------- W[K][N] fp32 -> WT[N][K] bf16 ----------------
__global__ void wt_kernel(const float* __restrict__ W, __bf16* __restrict__ WT,
                          int K, int N) {
    int idx = blockIdx.x * 256 + threadIdx.x;
    if (idx < K * N) {
        int k = idx / N, n = idx - k * N;
        WT[(size_t)n * K + k] = (__bf16)W[idx];
    }
}

// ---------------- bf16 MFMA GEMM (128x128 tile, BK=32, reg-staged LDS) ------
__global__ __launch_bounds__(256) void mfma_gemm(
    const __bf16* __restrict__ A, const __bf16* __restrict__ BT,
    const float* __restrict__ bias, void* __restrict__ C,
    int M, int N, int K, int do_elu, int out_bf16)
{
    __shared__ unsigned short lds[2 * 128 * 40];
    const int tid  = threadIdx.x;
    const int lane = tid & 63, wave = tid >> 6;
    const int wr = wave >> 1, wc = wave & 1;
    const int m0 = blockIdx.x * 128, n0 = blockIdx.y * 128;

    size_t offA[2], offB[2];
    int dstA[2], dstB[2];
    #pragma unroll
    for (int i = 0; i < 2; ++i) {
        int s = tid + i * 256;
        int r = s >> 2, ks = s & 3;
        int gr = m0 + r; if (gr > M - 1) gr = M - 1;
        offA[i] = (size_t)gr * K + ks * 8;
        dstA[i] = r * 40 + ks * 8;
        int gc = n0 + r; if (gc > N - 1) gc = N - 1;
        offB[i] = (size_t)gc * K + ks * 8;
        dstB[i] = 5120 + r * 40 + ks * 8;
    }

    v4f acc[4][4] = {};
    const int l15 = lane & 15, l4 = lane >> 4;
    const int abase = (wr * 64 + l15) * 40 + l4 * 8;
    const int bbase = 5120 + (wc * 64 + l15) * 40 + l4 * 8;

    u16x8 sa0 = *(const u16x8*)(A + offA[0]);
    u16x8 sa1 = *(const u16x8*)(A + offA[1]);
    u16x8 sb0 = *(const u16x8*)(BT + offB[0]);
    u16x8 sb1 = *(const u16x8*)(BT + offB[1]);

    for (int k0 = 0; k0 < K; k0 += 32) {
        __syncthreads();
        *(u16x8*)&lds[dstA[0]] = sa0;
        *(u16x8*)&lds[dstA[1]] = sa1;
        *(u16x8*)&lds[dstB[0]] = sb0;
        *(u16x8*)&lds[dstB[1]] = sb1;
        if (k0 + 32 < K) {
            sa0 = *(const u16x8*)(A + offA[0] + k0 + 32);
            sa1 = *(const u16x8*)(A + offA[1] + k0 + 32);
            sb0 = *(const u16x8*)(BT + offB[0] + k0 + 32);
            sb1 = *(const u16x8*)(BT + offB[1] + k0 + 32);
        }
        __syncthreads();
        v8bf af[4], bfr[4];
        #pragma unroll
        for (int m = 0; m < 4; ++m) af[m]  = *(const v8bf*)&lds[abase + m * 16 * 40];
        #pragma unroll
        for (int n = 0; n < 4; ++n) bfr[n] = *(const v8bf*)&lds[bbase + n * 16 * 40];
        #pragma unroll
        for (int m = 0; m < 4; ++m)
            #pragma unroll
            for (int n = 0; n < 4; ++n)
                acc[m][n] = __builtin_amdgcn_mfma_f32_16x16x32_bf16(af[m], bfr[n], acc[m][n], 0, 0, 0);
    }

    #pragma unroll
    for (int m = 0; m < 4; ++m) {
        #pragma unroll
        for (int j = 0; j < 4; ++j) {
            int row = m0 + wr * 64 + m * 16 + l4 * 4 + j;
            if (row >= M) continue;
            #pragma unroll
            for (int n = 0; n < 4; ++n) {
                int col = n0 + wc * 64 + n * 16 + l15;
                if (col >= N) continue;
                float v = acc[m][n][j] + bias[col];
                if (do_elu) v = elu_f(v);
                if (out_bf16) ((__bf16*)C)[(size_t)row * N + col] = (__bf16)v;
                else          ((float*)C)[(size_t)row * N + col] = v;
            }
        }
    }
}

// ---------------- small fp32 GEMM, epilogue: v = (acc [+bias]) [*scale[m]] ---
__global__ void gemm_kernel(const float* __restrict__ A, const float* __restrict__ W,
                            const float* __restrict__ bias, const float* __restrict__ scale,
                            float* __restrict__ C, int M, int N, int K, int do_elu) {
    const int BM = 64, BN = 64, BK = 16;
    __shared__ float As[BK][BM + 4];
    __shared__ float Ws[BK][BN + 4];
    int tid = threadIdx.x;
    int tx = tid & 15, ty = tid >> 4;
    int m0 = blockIdx.x * BM;
    int n0 = blockIdx.y * BN;
    float acc[4][4] = {};
    for (int k0 = 0; k0 < K; k0 += BK) {
        #pragma unroll
        for (int l = 0; l < 4; ++l) {
            int idx = tid + l * 256;
            int r = idx >> 4, c = idx & 15;
            int m = m0 + r;
            As[c][r] = (m < M) ? A[(size_t)m * K + k0 + c] : 0.f;
        }
        #pragma unroll
        for (int l = 0; l < 4; ++l) {
            int idx = tid + l * 256;
            int c = idx >> 6, n = idx & 63;
            int nn = n0 + n;
            Ws[c][n] = (nn < N) ? W[(size_t)(k0 + c) * N + nn] : 0.f;
        }
        __syncthreads();
        #pragma unroll
        for (int kk = 0; kk < BK; ++kk) {
            float4 av = *(const float4*)&As[kk][ty * 4];
            float4 wv = *(const float4*)&Ws[kk][tx * 4];
            float ar[4] = {av.x, av.y, av.z, av.w};
            float wrg[4] = {wv.x, wv.y, wv.z, wv.w};
            #pragma unroll
            for (int i = 0; i < 4; ++i)
                #pragma unroll
                for (int j = 0; j < 4; ++j)
                    acc[i][j] += ar[i] * wrg[j];
        }
        __syncthreads();
    }
    #pragma unroll
    for (int i = 0; i < 4; ++i) {
        int m = m0 + ty * 4 + i;
        if (m >= M) continue;
        float sc = scale ? scale[m] : 1.f;
        #pragma unroll
        for (int j = 0; j < 4; ++j) {
            int n = n0 + tx * 4 + j;
            if (n >= N) continue;
            float v = acc[i][j] + (bias ? bias[n] : 0.f);
            if (do_elu) v = elu_f(v);
            C[(size_t)m * N + n] = v * sc;
        }
    }
}

// ---------------- CSR build ----------------
__global__ void zero_cnt_kernel(int* __restrict__ cnt) {
    int i = blockIdx.x * 256 + threadIdx.x;
    if (i < N_NODES) cnt[i] = 0;
}
__global__ void cnt_kernel(const int* __restrict__ col, int* __restrict__ cnt) {
    int e = blockIdx.x * 256 + threadIdx.x;
    if (e < N_EDGES) atomicAdd(&cnt[col[e]], 1);
}
// per-block exclusive scan (512 elems/block), Hillis-Steele in LDS
__global__ void scan_a_kernel(const int* __restrict__ cnt, int* __restrict__ pp,
                              int* __restrict__ bs) {
    __shared__ int s[512];
    int t = threadIdx.x;
    int i = blockIdx.x * 512 + t;
    int v = (i < N_NODES) ? cnt[i] : 0;
    s[t] = v;
    __syncthreads();
    for (int off = 1; off < 512; off <<= 1) {
        int u = (t >= off) ? s[t - off] : 0;
        __syncthreads();
        s[t] += u;
        __syncthreads();
    }
    if (i < N_NODES) pp[i] = s[t] - v;
    if (t == 511) bs[blockIdx.x] = s[511];
}
// scan the 98 block sums (single block)
__global__ void scan_b_kernel(int* __restrict__ bs, int* __restrict__ ptr, int nblk) {
    __shared__ int s[128];
    int t = threadIdx.x;
    int v = (t < nblk) ? bs[t] : 0;
    s[t] = v;
    __syncthreads();
    for (int off = 1; off < 128; off <<= 1) {
        int u = (t >= off) ? s[t - off] : 0;
        __syncthreads();
        s[t] += u;
        __syncthreads();
    }
    if (t < nblk) bs[t] = s[t] - v;
    if (t == 127) ptr[N_NODES] = s[127];
}
// finalize: ptr = fill = pp + blockoffset ; dis = rsqrt(deg+1)
__global__ void scan_c_kernel(const int* __restrict__ pp, const int* __restrict__ bs,
                              const int* __restrict__ cnt, int* __restrict__ ptr,
                              int* __restrict__ fill, float* __restrict__ dis) {
    int i = blockIdx.x * 256 + threadIdx.x;
    if (i < N_NODES) {
        int p = pp[i] + bs[i >> 9];
        ptr[i] = p;
        fill[i] = p;
        dis[i] = rsqrtf((float)(cnt[i] + 1));
    }
}
__global__ void scatter_kernel(const int* __restrict__ row, const int* __restrict__ col,
                               int* __restrict__ fill, int* __restrict__ csr) {
    int e = blockIdx.x * 256 + threadIdx.x;
    if (e < N_EDGES) {
        int pos = atomicAdd(&fill[col[e]], 1);
        csr[pos] = row[e];
    }
}

// ---------------- CSR gather aggregation ----------------
// thread = (node, feat); xws already scaled by dis[row]; self-loop = own row.
__global__ void gather_kernel(const float* __restrict__ xws, const int* __restrict__ csr,
                              const int* __restrict__ ptr, const float* __restrict__ dis,
                              const float* __restrict__ bias, float* __restrict__ out,
                              int fshift, int do_elu) {
    int idx = blockIdx.x * 256 + threadIdx.x;
    int node = idx >> fshift;
    if (node >= N_NODES) return;
    int f = idx & ((1 << fshift) - 1);
    int s = ptr[node], e = ptr[node + 1];
    float acc = xws[((size_t)node << fshift) + f];  // self-loop (dis[node]*xw[node])
    for (int i = s; i < e; ++i) {
        int r = csr[i];
        acc += xws[((size_t)r << fshift) + f];
    }
    float v = dis[node] * acc + bias[f];
    out[idx] = do_elu ? elu_f(v) : v;
}

extern "C" void kernel_launch(void* const* d_in, const int* in_sizes, int n_in,
                              void* d_out, int out_size, void* d_ws, size_t ws_size,
                              hipStream_t stream) {
    const float* x    = (const float*)d_in[0];
    const int*   ei   = (const int*)d_in[1];
    const int*   row  = ei;
    const int*   col  = ei + N_EDGES;
    const float* ln_w = (const float*)d_in[2];
    const float* ln_b = (const float*)d_in[3];
    const float* w0   = (const float*)d_in[4];
    const float* b0   = (const float*)d_in[5];
    const float* w1   = (const float*)d_in[6];
    const float* b1   = (const float*)d_in[7];
    const float* w2   = (const float*)d_in[8];
    const float* b2   = (const float*)d_in[9];
    const float* g1w  = (const float*)d_in[10];
    const float* g1b  = (const float*)d_in[11];
    const float* g2w  = (const float*)d_in[12];
    const float* g2b  = (const float*)d_in[13];
    float* out = (float*)d_out;

    char* W = (char*)d_ws;
    __bf16* h0  = (__bf16*)(W + 0);          // 50000*1024 bf16 (dead after GEMM0)
    __bf16* h1  = (__bf16*)(W + 102400000);  // 50000*512 bf16
    __bf16* h2  = (__bf16*)(W + 153600000);  // 50000*128 bf16
    float*  h3  = (float*) (W + 166400000);  // 50000*64 f32
    float*  dis = (float*) (W + 179200000);  // 50000 f32
    float*  xw1 = (float*) (W + 179400192);  // 50000*32 f32 (dis-scaled)
    float*  agg1= (float*) (W + 185800192);  // 50000*32 f32
    float*  xw2 = (float*) (W + 192200192);  // 50000*16 f32 (dis-scaled)
    __bf16* w0t = (__bf16*)(W + 195400192);  // 512*1024 bf16
    __bf16* w1t = (__bf16*)(W + 196448768);  // 128*512 bf16
    __bf16* w2t = (__bf16*)(W + 196579840);  // 64*128 bf16
    // CSR structures overlay h0 (written only after GEMM0 consumed h0)
    int*    csr = (int*)(W + 0);             // 3.2M int
    int*    ptr = (int*)(W + 12800000);      // 50001 int
    int*    fill= (int*)(W + 13000064);      // 50000 int
    int*    pp  = (int*)(W + 13200128);      // 50000 int
    int*    bs  = (int*)(W + 13400192);      // 128 int
    int*    cnt = (int*)(W + 13600256);      // 50000 int

    const int NBLK_SCAN = (N_NODES + 511) / 512;  // 98

    // weight transposes (tiny)
    wt_kernel<<<(1024 * 512 + 255) / 256, 256, 0, stream>>>(w0, w0t, 1024, 512);
    wt_kernel<<<(512 * 128 + 255) / 256, 256, 0, stream>>>(w1, w1t, 512, 128);
    wt_kernel<<<(128 * 64 + 255) / 256, 256, 0, stream>>>(w2, w2t, 128, 64);

    // 1. pool + layernorm -> bf16
    pool_ln_kernel<<<N_NODES, 256, 0, stream>>>(x, ln_w, ln_b, h0);

    // 2. GEMM0 (h0 -> h1); h0 dead afterwards
    {
        dim3 g((N_NODES + 127) / 128, 4);
        mfma_gemm<<<g, 256, 0, stream>>>(h0, w0t, b0, h1, N_NODES, 512, 1024, 1, 1);
    }

    // 3. CSR build (overlays h0 region)
    zero_cnt_kernel<<<(N_NODES + 255) / 256, 256, 0, stream>>>(cnt);
    cnt_kernel<<<(N_EDGES + 255) / 256, 256, 0, stream>>>(col, cnt);
    scan_a_kernel<<<NBLK_SCAN, 512, 0, stream>>>(cnt, pp, bs);
    scan_b_kernel<<<1, 128, 0, stream>>>(bs, ptr, NBLK_SCAN);
    scan_c_kernel<<<(N_NODES + 255) / 256, 256, 0, stream>>>(pp, bs, cnt, ptr, fill, dis);
    scatter_kernel<<<(N_EDGES + 255) / 256, 256, 0, stream>>>(row, col, fill, csr);

    // 4. rest of MLP
    {
        dim3 g((N_NODES + 127) / 128, 1);
        mfma_gemm<<<g, 256, 0, stream>>>(h1, w1t, b1, h2, N_NODES, 128, 512, 1, 1);
    }
    {
        dim3 g((N_NODES + 127) / 128, 1);
        mfma_gemm<<<g, 256, 0, stream>>>(h2, w2t, b2, h3, N_NODES, 64, 128, 1, 0);
    }

    // 5. GCN1: xw1 = dis[r] * (h3 @ g1w); gather; +bias, ELU
    {
        dim3 g((N_NODES + 63) / 64, 1);
        gemm_kernel<<<g, 256, 0, stream>>>(h3, g1w, nullptr, dis, xw1, N_NODES, 32, 64, 0);
    }
    gather_kernel<<<((N_NODES * 32) + 255) / 256, 256, 0, stream>>>(
        xw1, csr, ptr, dis, g1b, agg1, 5, 1);

    // 6. GCN2: xw2 = dis[r] * (agg1 @ g2w); gather into out; +bias
    {
        dim3 g((N_NODES + 63) / 64, 1);
        gemm_kernel<<<g, 256, 0, stream>>>(agg1, g2w, nullptr, dis, xw2, N_NODES, 16, 32, 0);
    }
    gather_kernel<<<((N_NODES * 16) + 255) / 256, 256, 0, stream>>>(
        xw2, csr, ptr, dis, g2b, out, 4, 0);
}